// Round 4
// baseline (366.491 us; speedup 1.0000x reference)
//
#include <hip/hip_runtime.h>
#include <hip/hip_bf16.h>
#include <math.h>

#define HID 128
#define NHEAD 8
#define HD 16
#define NL 3
#define NB 16
#define NS 256
#define ROWS (NB*NS)   // 4096

// ---------- fused LN + GEMM: C[64rows x Nc] = act( LN(x (+x2)) @ W )
// K = HID = 128 (full row per block). If nf != null (embed mode), the LN input
// is h = nf@Wn computed in-register (K=2), and block x==0 also writes h out.
// One __syncthreads total: LN->LDS staging, then single-shot K=128 GEMM.
__global__ __launch_bounds__(256) void k_lngemm(const float* __restrict__ x,
                                                const float* __restrict__ x2,
                                                const float* __restrict__ nf,
                                                const float* __restrict__ Wn,
                                                const float* __restrict__ g,
                                                const float* __restrict__ b,
                                                const float* __restrict__ W,
                                                float* __restrict__ C,
                                                float* __restrict__ hout,
                                                int Nc, int relu) {
    __shared__ float Ast[HID][72];   // [k][m] transposed LN'd A-tile (36.9 KB)
    __shared__ float Ws[HID][68];    // [k][n] W-tile (34.8 KB)
    int t = threadIdx.x;
    int row0 = blockIdx.y * 64, col0 = blockIdx.x * 64;

    // ---- stage W: 128 x 64, 8 float4 per thread, coalesced
    {
        int wk0 = t >> 3, wn = (t & 7) * 8;
#pragma unroll
        for (int rep = 0; rep < 4; ++rep) {
            int wk = wk0 + rep * 32;
            const float* wp = W + (long)wk * Nc + col0 + wn;
            *(float4*)&Ws[wk][wn]     = *(const float4*)wp;
            *(float4*)&Ws[wk][wn + 4] = *(const float4*)(wp + 4);
        }
    }

    // ---- embed mode: write h coalesced (block x==0 only)
    if (nf && blockIdx.x == 0 && hout) {
        int row = row0 + (t >> 2), cb = (t & 3) * 32;
        float n0 = nf[2 * row], n1 = nf[2 * row + 1];
#pragma unroll
        for (int j = 0; j < 32; j += 4) {
            float4 v;
            v.x = n0 * Wn[cb + j + 0] + n1 * Wn[HID + cb + j + 0];
            v.y = n0 * Wn[cb + j + 1] + n1 * Wn[HID + cb + j + 1];
            v.z = n0 * Wn[cb + j + 2] + n1 * Wn[HID + cb + j + 2];
            v.w = n0 * Wn[cb + j + 3] + n1 * Wn[HID + cb + j + 3];
            *(float4*)&hout[(long)row * HID + cb + j] = v;
        }
    }

    // ---- LN: 2 passes x 32 rows; 8 threads per row, 16 cols each (coalesced)
#pragma unroll
    for (int pass = 0; pass < 2; ++pass) {
        int row = pass * 32 + (t >> 3);       // tile-local row
        int p   = t & 7;                       // col-part
        int cb  = p * 16;
        float v[16];
        if (nf) {
            float n0 = nf[2 * (row0 + row)], n1 = nf[2 * (row0 + row) + 1];
#pragma unroll
            for (int j = 0; j < 16; ++j) v[j] = n0 * Wn[cb + j] + n1 * Wn[HID + cb + j];
        } else {
            const float* xp = x + (long)(row0 + row) * HID + cb;
#pragma unroll
            for (int j = 0; j < 16; j += 4) *(float4*)&v[j] = *(const float4*)(xp + j);
            if (x2) {
                const float* yp = x2 + (long)(row0 + row) * HID + cb;
#pragma unroll
                for (int j = 0; j < 16; j += 4) {
                    float4 r4 = *(const float4*)(yp + j);
                    v[j] += r4.x; v[j+1] += r4.y; v[j+2] += r4.z; v[j+3] += r4.w;
                }
            }
        }
        float s = 0.f, s2 = 0.f;
#pragma unroll
        for (int j = 0; j < 16; ++j) { s += v[j]; s2 += v[j] * v[j]; }
        s  += __shfl_xor(s, 1);  s  += __shfl_xor(s, 2);  s  += __shfl_xor(s, 4);
        s2 += __shfl_xor(s2, 1); s2 += __shfl_xor(s2, 2); s2 += __shfl_xor(s2, 4);
        float mu  = s * (1.f / HID);
        float var = s2 * (1.f / HID) - mu * mu;
        float inv = rsqrtf(var + 1e-5f);
        // write transposed, j rotated by p to spread banks (2-way max)
#pragma unroll
        for (int jj = 0; jj < 16; ++jj) {
            int j = (jj + p) & 15;
            int c = cb + j;
            Ast[c][row] = (v[j] - mu) * inv * g[c] + b[c];
        }
    }
    __syncthreads();

    // ---- single-shot K=128 GEMM, 4x4 microtile
    int tx = t & 15, ty = t >> 4;
    float acc[4][4] = {};
#pragma unroll 8
    for (int k = 0; k < HID; ++k) {
        float4 a4 = *(const float4*)&Ast[k][ty * 4];
        float4 w4 = *(const float4*)&Ws[k][tx * 4];
        acc[0][0] += a4.x * w4.x; acc[0][1] += a4.x * w4.y; acc[0][2] += a4.x * w4.z; acc[0][3] += a4.x * w4.w;
        acc[1][0] += a4.y * w4.x; acc[1][1] += a4.y * w4.y; acc[1][2] += a4.y * w4.z; acc[1][3] += a4.y * w4.w;
        acc[2][0] += a4.z * w4.x; acc[2][1] += a4.z * w4.y; acc[2][2] += a4.z * w4.z; acc[2][3] += a4.z * w4.w;
        acc[3][0] += a4.w * w4.x; acc[3][1] += a4.w * w4.y; acc[3][2] += a4.w * w4.z; acc[3][3] += a4.w * w4.w;
    }
#pragma unroll
    for (int i = 0; i < 4; ++i) {
        int row = row0 + ty * 4 + i;
        int col = col0 + tx * 4;
        float4 v = make_float4(acc[i][0], acc[i][1], acc[i][2], acc[i][3]);
        if (relu) { v.x = fmaxf(v.x, 0.f); v.y = fmaxf(v.y, 0.f); v.z = fmaxf(v.z, 0.f); v.w = fmaxf(v.w, 0.f); }
        *(float4*)(C + (long)row * Nc + col) = v;
    }
}

// ---------- plain GEMM (W2): C = A @ W + res, BK=32 staged loop
__global__ __launch_bounds__(256) void k_gemm(const float* __restrict__ A,
                                              const float* __restrict__ W,
                                              float* __restrict__ C,
                                              const float* __restrict__ res,
                                              int M, int Nc, int K, int relu) {
    __shared__ float Ast[32][72];  // [k][m]
    __shared__ float Ws[32][68];   // [k][n]
    int t = threadIdx.x;
    int row0 = blockIdx.y * 64, col0 = blockIdx.x * 64;
    int tx = t & 15, ty = t >> 4;
    float acc[4][4] = {};
    int am = t >> 2, ak = (t & 3) * 8;
    int wk = t >> 3, wn = (t & 7) * 8;
    for (int kc = 0; kc < K; kc += 32) {
        const float* ap = A + (long)(row0 + am) * K + kc + ak;
        float4 a0 = *(const float4*)ap;
        float4 a1 = *(const float4*)(ap + 4);
        const float* wp = W + (long)(kc + wk) * Nc + col0 + wn;
        float4 w0 = *(const float4*)wp;
        float4 w1 = *(const float4*)(wp + 4);
        Ast[ak + 0][am] = a0.x; Ast[ak + 1][am] = a0.y; Ast[ak + 2][am] = a0.z; Ast[ak + 3][am] = a0.w;
        Ast[ak + 4][am] = a1.x; Ast[ak + 5][am] = a1.y; Ast[ak + 6][am] = a1.z; Ast[ak + 7][am] = a1.w;
        *(float4*)&Ws[wk][wn]     = w0;
        *(float4*)&Ws[wk][wn + 4] = w1;
        __syncthreads();
#pragma unroll
        for (int k = 0; k < 32; ++k) {
            float4 a4 = *(const float4*)&Ast[k][ty * 4];
            float4 w4 = *(const float4*)&Ws[k][tx * 4];
            acc[0][0] += a4.x * w4.x; acc[0][1] += a4.x * w4.y; acc[0][2] += a4.x * w4.z; acc[0][3] += a4.x * w4.w;
            acc[1][0] += a4.y * w4.x; acc[1][1] += a4.y * w4.y; acc[1][2] += a4.y * w4.z; acc[1][3] += a4.y * w4.w;
            acc[2][0] += a4.z * w4.x; acc[2][1] += a4.z * w4.y; acc[2][2] += a4.z * w4.z; acc[2][3] += a4.z * w4.w;
            acc[3][0] += a4.w * w4.x; acc[3][1] += a4.w * w4.y; acc[3][2] += a4.w * w4.z; acc[3][3] += a4.w * w4.w;
        }
        __syncthreads();
    }
#pragma unroll
    for (int i = 0; i < 4; ++i) {
        int row = row0 + ty * 4 + i;
        int col = col0 + tx * 4;
        float4 v = make_float4(acc[i][0], acc[i][1], acc[i][2], acc[i][3]);
        if (res) {
            float4 r4 = *(const float4*)(res + (long)row * Nc + col);
            v.x += r4.x; v.y += r4.y; v.z += r4.z; v.w += r4.w;
        }
        if (relu) { v.x = fmaxf(v.x, 0.f); v.y = fmaxf(v.y, 0.f); v.z = fmaxf(v.z, 0.f); v.w = fmaxf(v.w, 0.f); }
        *(float4*)(C + (long)row * Nc + col) = v;
    }
}

// ---------- attention: grid 512 = b(16) x head(8) x quarter(4); 256 thr.
// Edge scalars (rank-1 collapse of e@We) computed inline per block.
__global__ __launch_bounds__(256) void k_attn(const float* __restrict__ qkv,
                                              const float* __restrict__ ef,
                                              const float* __restrict__ We_in,
                                              const float* __restrict__ We,
                                              int layer,
                                              float* __restrict__ y) {
    __shared__ float Ks[NS][20];        // [col][d]
    __shared__ float Vt[HD][NS + 4];    // transposed V: [d][col]
    __shared__ float Pb[4][4][NS];      // per-wave, per-row prob rows
    __shared__ float sred[2][2];
    int bid = blockIdx.x;
    int q4 = bid & 3, hh = (bid >> 2) & 7, bb = bid >> 5;
    int t = threadIdx.x;
    int w = t >> 6, lane = t & 63;
    {   // K/V staging: one row per thread
        const float* kr = qkv + ((long)(bb * NS + t)) * 384 + HID + hh * HD;
        *(float4*)&Ks[t][0]  = *(const float4*)kr;
        *(float4*)&Ks[t][4]  = *(const float4*)(kr + 4);
        *(float4*)&Ks[t][8]  = *(const float4*)(kr + 8);
        *(float4*)&Ks[t][12] = *(const float4*)(kr + 12);
        const float* vr = kr + HID;
        float vv[16];
        *(float4*)&vv[0]  = *(const float4*)vr;
        *(float4*)&vv[4]  = *(const float4*)(vr + 4);
        *(float4*)&vv[8]  = *(const float4*)(vr + 8);
        *(float4*)&vv[12] = *(const float4*)(vr + 12);
#pragma unroll
        for (int d = 0; d < 16; ++d) Vt[d][t] = vv[d];
    }
    {   // inline edge scalars: s1 = We_in . We[l][:,hh], s2 = We_in . We[l][:,8+hh]
        if (w < 2) {
            int c = w * 64 + lane;
            const float* wrow = We + ((long)layer * HID + c) * (2 * NHEAD);
            float p1 = We_in[c] * wrow[hh];
            float p2 = We_in[c] * wrow[NHEAD + hh];
#pragma unroll
            for (int o = 32; o; o >>= 1) { p1 += __shfl_xor(p1, o); p2 += __shfl_xor(p2, o); }
            if (lane == 0) { sred[w][0] = p1; sred[w][1] = p2; }
        }
    }
    __syncthreads();
    float s1  = sred[0][0] + sred[1][0];
    float s2g = sred[0][1] + sred[1][1];
    int part = lane >> 4, dd = lane & 15;
    for (int it = 0; it < 4; ++it) {
        int r0 = q4 * 64 + w * 16 + it * 4;
        float q[4][16];
#pragma unroll
        for (int rr = 0; rr < 4; ++rr) {
            const float* qr = qkv + ((long)(bb * NS + r0 + rr)) * 384 + hh * HD;
            *(float4*)&q[rr][0]  = *(const float4*)qr;
            *(float4*)&q[rr][4]  = *(const float4*)(qr + 4);
            *(float4*)&q[rr][8]  = *(const float4*)(qr + 8);
            *(float4*)&q[rr][12] = *(const float4*)(qr + 12);
        }
        float sc[4][4];
#pragma unroll
        for (int i = 0; i < 4; ++i) {
            int c = i * 64 + lane;
            float kk[16];
            *(float4*)&kk[0]  = *(const float4*)&Ks[c][0];
            *(float4*)&kk[4]  = *(const float4*)&Ks[c][4];
            *(float4*)&kk[8]  = *(const float4*)&Ks[c][8];
            *(float4*)&kk[12] = *(const float4*)&Ks[c][12];
#pragma unroll
            for (int rr = 0; rr < 4; ++rr) {
                float d0 = 0.f;
#pragma unroll
                for (int d = 0; d < 16; ++d) d0 += q[rr][d] * kk[d];
                sc[rr][i] = d0;
            }
        }
#pragma unroll
        for (int rr = 0; rr < 4; ++rr) {
            int row = r0 + rr;
            long eb = ((long)(bb * NS + row)) * NS;
            float e0 = ef[eb + lane],       e1 = ef[eb + 64 + lane];
            float e2 = ef[eb + 128 + lane], e3 = ef[eb + 192 + lane];
            float x0 = sc[rr][0] * 0.25f + e0 * s1;
            float x1 = sc[rr][1] * 0.25f + e1 * s1;
            float x2 = sc[rr][2] * 0.25f + e2 * s1;
            float x3 = sc[rr][3] * 0.25f + e3 * s1;
            float m = fmaxf(fmaxf(x0, x1), fmaxf(x2, x3));
#pragma unroll
            for (int o = 32; o; o >>= 1) m = fmaxf(m, __shfl_xor(m, o));
            float p0 = __expf(x0 - m), p1 = __expf(x1 - m);
            float p2 = __expf(x2 - m), p3 = __expf(x3 - m);
            float sum = p0 + p1 + p2 + p3;
#pragma unroll
            for (int o = 32; o; o >>= 1) sum += __shfl_xor(sum, o);
            float inv = s2g / sum;
            Pb[w][rr][lane]       = p0 * inv * e0;
            Pb[w][rr][64 + lane]  = p1 * inv * e1;
            Pb[w][rr][128 + lane] = p2 * inv * e2;
            Pb[w][rr][192 + lane] = p3 * inv * e3;
        }
        __syncthreads();
        float a0 = 0.f, a1 = 0.f, a2 = 0.f, a3 = 0.f;
#pragma unroll
        for (int ii = 0; ii < 16; ++ii) {
            int c = part * 64 + ((ii + part * 4) & 15) * 4;
            float4 vv = *(const float4*)&Vt[dd][c];
            float4 p;
            p = *(const float4*)&Pb[w][0][c]; a0 += vv.x * p.x + vv.y * p.y + vv.z * p.z + vv.w * p.w;
            p = *(const float4*)&Pb[w][1][c]; a1 += vv.x * p.x + vv.y * p.y + vv.z * p.z + vv.w * p.w;
            p = *(const float4*)&Pb[w][2][c]; a2 += vv.x * p.x + vv.y * p.y + vv.z * p.z + vv.w * p.w;
            p = *(const float4*)&Pb[w][3][c]; a3 += vv.x * p.x + vv.y * p.y + vv.z * p.z + vv.w * p.w;
        }
        a0 += __shfl_xor(a0, 16); a0 += __shfl_xor(a0, 32);
        a1 += __shfl_xor(a1, 16); a1 += __shfl_xor(a1, 32);
        a2 += __shfl_xor(a2, 16); a2 += __shfl_xor(a2, 32);
        a3 += __shfl_xor(a3, 16); a3 += __shfl_xor(a3, 32);
        if (lane < 16) {
            y[((long)(bb * NS + r0 + 0)) * HID + hh * HD + dd] = a0;
            y[((long)(bb * NS + r0 + 1)) * HID + hh * HD + dd] = a1;
            y[((long)(bb * NS + r0 + 2)) * HID + hh * HD + dd] = a2;
            y[((long)(bb * NS + r0 + 3)) * HID + hh * HD + dd] = a3;
        }
        __syncthreads();
    }
}

// ---------- out = 10*tanh((h @ Wdec)/sqrt(128)), one wave per row
__global__ __launch_bounds__(256) void k_dec(const float* __restrict__ h,
                                             const float* __restrict__ Wdec,
                                             float* __restrict__ out) {
    int w = threadIdx.x >> 6, lane = threadIdx.x & 63;
    int row = blockIdx.x * 4 + w;
    float a = h[(long)row * HID + lane] * Wdec[lane]
            + h[(long)row * HID + 64 + lane] * Wdec[64 + lane];
#pragma unroll
    for (int o = 32; o; o >>= 1) a += __shfl_xor(a, o);
    if (lane == 0) out[row] = 10.f * tanhf(a * 0.08838834764831845f);
}

extern "C" void kernel_launch(void* const* d_in, const int* in_sizes, int n_in,
                              void* d_out, int out_size, void* d_ws, size_t ws_size,
                              hipStream_t stream) {
    const float* nf    = (const float*)d_in[0];
    const float* ef    = (const float*)d_in[1];
    const float* Wn    = (const float*)d_in[2];
    const float* We_in = (const float*)d_in[3];
    const float* ln1g  = (const float*)d_in[4];
    const float* ln1b  = (const float*)d_in[5];
    const float* Wh    = (const float*)d_in[6];
    const float* We    = (const float*)d_in[7];
    const float* ln2g  = (const float*)d_in[8];
    const float* ln2b  = (const float*)d_in[9];
    const float* W1    = (const float*)d_in[10];
    const float* W2    = (const float*)d_in[11];
    const float* Wdec  = (const float*)d_in[12];

    float* ws   = (float*)d_ws;
    float* h    = ws;                 // 4096*128
    float* y    = h + ROWS * HID;     // 4096*128
    float* big  = y + ROWS * HID;     // 4096*512 (qkv / mlp hidden)

    for (int l = 0; l < NL; ++l) {
        // LN1 + QKV GEMM (layer 0: embed fused, writes h)
        k_lngemm<<<dim3(6, 64), 256, 0, stream>>>(
            h, nullptr, (l == 0) ? nf : nullptr, Wn,
            ln1g + l * HID, ln1b + l * HID,
            Wh + (long)l * HID * 384, big, (l == 0) ? h : nullptr, 384, 0);
        k_attn<<<512, 256, 0, stream>>>(big, ef, We_in, We, l, y);
        // LN2(y + h) + W1 GEMM + relu
        k_lngemm<<<dim3(8, 64), 256, 0, stream>>>(
            y, h, nullptr, Wn,
            ln2g + l * HID, ln2b + l * HID,
            W1 + (long)l * HID * 512, big, nullptr, 512, 1);
        // W2 GEMM + residual y -> h
        k_gemm<<<dim3(2, 64), 256, 0, stream>>>(big, W2 + (long)l * 512 * HID, h, y, ROWS, HID, 512, 0);
    }
    k_dec<<<ROWS / 4, 256, 0, stream>>>(h, Wdec, (float*)d_out);
}